// Round 1
// baseline (116.571 us; speedup 1.0000x reference)
//
#include <hip/hip_runtime.h>
#include <hip/hip_bf16.h>

// Problem constants (B=1)
#define NTOK   384
#define DNODE  256
#define DPAIR  128
#define DHID   32
#define NOUT   49152   // NTOK * DPAIR, columns of the big GEMM
static constexpr float LN_EPS = 1e-5f;

typedef __bf16 bf16x8 __attribute__((ext_vector_type(8)));
typedef float  f32x4  __attribute__((ext_vector_type(4)));

// ---------------------------------------------------------------------------
// Kernel 1: LayerNorm + projections a = sn@Wa^T + ba, b = sn@Wb^T + bb
//           (one block per token row), plus Wo fp32->bf16 cast (blocks >= 384).
// ---------------------------------------------------------------------------
__global__ __launch_bounds__(256) void k1_ln_proj(
    const float* __restrict__ s, const float* __restrict__ gamma,
    const float* __restrict__ beta,
    const float* __restrict__ Wa, const float* __restrict__ ba,
    const float* __restrict__ Wb, const float* __restrict__ bb,
    const float* __restrict__ Wo,
    __bf16* __restrict__ a_vec, __bf16* __restrict__ b_vec,
    __bf16* __restrict__ wo_bf)
{
    const int t = threadIdx.x;
    const int blk = blockIdx.x;

    if (blk >= NTOK) {
        // Convert Wo (128*1024 fp32) to bf16, coalesced. 128 blocks * 1024 elems.
        const int base = (blk - NTOK) * 1024 + t;
        #pragma unroll
        for (int i = 0; i < 4; ++i)
            wo_bf[base + i * 256] = (__bf16)Wo[base + i * 256];
        return;
    }

    __shared__ __align__(16) float sn[DNODE];
    __shared__ float red[8];

    const float x = s[blk * DNODE + t];
    float v0 = x, v1 = x * x;
    #pragma unroll
    for (int off = 32; off > 0; off >>= 1) {
        v0 += __shfl_down(v0, off, 64);
        v1 += __shfl_down(v1, off, 64);
    }
    if ((t & 63) == 0) { red[(t >> 6) * 2] = v0; red[(t >> 6) * 2 + 1] = v1; }
    __syncthreads();
    const float sum   = red[0] + red[2] + red[4] + red[6];
    const float sumsq = red[1] + red[3] + red[5] + red[7];
    const float mu  = sum * (1.0f / DNODE);
    const float var = sumsq * (1.0f / DNODE) - mu * mu;
    const float inv = rsqrtf(var + LN_EPS);
    sn[t] = (x - mu) * inv * gamma[t] + beta[t];
    __syncthreads();

    // 64 outputs (32 for a, 32 for b); 4 threads per output, 64 terms each.
    const int o = t >> 2, part = t & 3;
    const float* Wrow = (o < DHID) ? (Wa + (size_t)o * DNODE)
                                   : (Wb + (size_t)(o - DHID) * DNODE);
    const int base = part * 64;
    float acc = 0.f;
    #pragma unroll
    for (int k = 0; k < 64; k += 4) {
        const float4 w  = *(const float4*)(Wrow + base + k);
        const float4 xs = *(const float4*)(sn + base + k);
        acc += w.x * xs.x + w.y * xs.y + w.z * xs.z + w.w * xs.w;
    }
    acc += __shfl_xor(acc, 1, 64);
    acc += __shfl_xor(acc, 2, 64);
    if (part == 0) {
        if (o < DHID) a_vec[blk * DHID + o]          = (__bf16)(acc + ba[o]);
        else          b_vec[blk * DHID + (o - DHID)] = (__bf16)(acc + bb[o - DHID]);
    }
}

// ---------------------------------------------------------------------------
// Kernel 2: T[j, (p,d)] = sum_e b[j,e] * Wo[p,d,e]  — MFMA GEMM M=384,N=4096,K=32
// One 16x16 tile per wave, single mfma (K=32). Output bf16, row-major [384][4096]
// => flat index ((j*128+p)*32 + d): exactly the B-operand layout kernel 3 needs.
// ---------------------------------------------------------------------------
__global__ __launch_bounds__(256) void k2_build_T(
    const __bf16* __restrict__ b_vec, const __bf16* __restrict__ wo_bf,
    __bf16* __restrict__ Tm)
{
    const int l = threadIdx.x & 63;
    const int w = threadIdx.x >> 6;
    const int j0 = blockIdx.y * 16;
    const int n0 = (blockIdx.x * 4 + w) * 16;
    const int row = l & 15, q = l >> 4, koff = q * 8;

    const bf16x8 af = *(const bf16x8*)(b_vec + (j0 + row) * DHID + koff);
    const bf16x8 bf = *(const bf16x8*)(wo_bf + (size_t)(n0 + row) * 32 + koff);
    f32x4 acc = {0.f, 0.f, 0.f, 0.f};
    acc = __builtin_amdgcn_mfma_f32_16x16x32_bf16(af, bf, acc, 0, 0, 0);

    const int col = n0 + row;
    #pragma unroll
    for (int r = 0; r < 4; ++r)
        Tm[(size_t)(j0 + q * 4 + r) * 4096 + col] = (__bf16)acc[r];
}

// ---------------------------------------------------------------------------
// Kernel 3: out[i, jp] = sum_d a[i,d] * T[jp,d] + bo[jp & 127]
// MFMA GEMM M=384, N=49152, K=32. One mfma per 16x16 tile; bias in acc init.
// No LDS: frag loads are contiguous 1KB/wave from L1/L2. NT stores (75.5 MB).
// ---------------------------------------------------------------------------
__global__ __launch_bounds__(256) void k3_main(
    const __bf16* __restrict__ a_vec, const __bf16* __restrict__ Tm,
    const float* __restrict__ bo, float* __restrict__ out)
{
    const int l = threadIdx.x & 63;
    const int w = threadIdx.x >> 6;
    const int i0 = blockIdx.y * 16;
    const int row = l & 15, q = l >> 4, koff = q * 8;

    const bf16x8 af = *(const bf16x8*)(a_vec + (i0 + row) * DHID + koff);

    const int ntb = blockIdx.x * 16 + w * 4;   // 4 consecutive n-tiles per wave
    #pragma unroll
    for (int tt = 0; tt < 4; ++tt) {
        const int n0 = (ntb + tt) * 16;
        const bf16x8 bf = *(const bf16x8*)(Tm + (size_t)(n0 + row) * 32 + koff);
        const float bv = bo[(n0 + row) & (DPAIR - 1)];
        f32x4 acc = {bv, bv, bv, bv};
        acc = __builtin_amdgcn_mfma_f32_16x16x32_bf16(af, bf, acc, 0, 0, 0);

        const size_t colbase = (size_t)n0 + row;
        #pragma unroll
        for (int r = 0; r < 4; ++r)
            __builtin_nontemporal_store(
                acc[r], out + (size_t)(i0 + q * 4 + r) * NOUT + colbase);
    }
}

// ---------------------------------------------------------------------------
extern "C" void kernel_launch(void* const* d_in, const int* in_sizes, int n_in,
                              void* d_out, int out_size, void* d_ws, size_t ws_size,
                              hipStream_t stream)
{
    const float* s     = (const float*)d_in[0];
    const float* gamma = (const float*)d_in[1];
    const float* beta  = (const float*)d_in[2];
    const float* Wa    = (const float*)d_in[3];
    const float* ba    = (const float*)d_in[4];
    const float* Wb    = (const float*)d_in[5];
    const float* bb    = (const float*)d_in[6];
    const float* Wo    = (const float*)d_in[7];
    const float* bo    = (const float*)d_in[8];
    float* out = (float*)d_out;

    // Workspace layout (all 16B-aligned offsets), total ~3.46 MB:
    char* ws = (char*)d_ws;
    __bf16* a_vec = (__bf16*)(ws);            // 384*32*2   = 24576 B
    __bf16* b_vec = (__bf16*)(ws + 24576);    // 384*32*2   = 24576 B
    __bf16* wo_bf = (__bf16*)(ws + 49152);    // 131072*2   = 262144 B
    __bf16* Tm    = (__bf16*)(ws + 311296);   // 384*4096*2 = 3145728 B

    // K1: 384 LN/proj blocks + 128 Wo-conversion blocks
    k1_ln_proj<<<512, 256, 0, stream>>>(s, gamma, beta, Wa, ba, Wb, bb, Wo,
                                        a_vec, b_vec, wo_bf);
    // K2: T  (M=384 j, N=4096 (p,d), K=32 e): 24 x 256 tiles, 4 waves/block
    k2_build_T<<<dim3(64, 24), 256, 0, stream>>>(b_vec, wo_bf, Tm);
    // K3: out (M=384 i, N=49152 (j,p), K=32 d): 24 x 3072 tiles
    k3_main<<<dim3(192, 24), 256, 0, stream>>>(a_vec, Tm, bo, out);
}

// Round 2
// 116.498 us; speedup vs baseline: 1.0006x; 1.0006x over previous
//
#include <hip/hip_runtime.h>
#include <hip/hip_bf16.h>

// Problem constants (B=1)
#define NTOK   384
#define DNODE  256
#define DPAIR  128
#define DHID   32
#define NOUT   49152   // NTOK * DPAIR, columns (fast axis) of the output
static constexpr float LN_EPS = 1e-5f;

typedef __bf16 bf16x8 __attribute__((ext_vector_type(8)));
typedef __bf16 bf16x4 __attribute__((ext_vector_type(4)));
typedef float  f32x4  __attribute__((ext_vector_type(4)));

// ---------------------------------------------------------------------------
// Kernel 1: LayerNorm + projections a = sn@Wa^T + ba, b = sn@Wb^T + bb
//           (one block per token row). Outputs bf16 [384][32] each.
// ---------------------------------------------------------------------------
__global__ __launch_bounds__(256) void k1_ln_proj(
    const float* __restrict__ s, const float* __restrict__ gamma,
    const float* __restrict__ beta,
    const float* __restrict__ Wa, const float* __restrict__ ba,
    const float* __restrict__ Wb, const float* __restrict__ bb,
    __bf16* __restrict__ a_vec, __bf16* __restrict__ b_vec)
{
    const int t = threadIdx.x;
    const int blk = blockIdx.x;

    __shared__ __align__(16) float sn[DNODE];
    __shared__ float red[8];

    const float x = s[blk * DNODE + t];
    float v0 = x, v1 = x * x;
    #pragma unroll
    for (int off = 32; off > 0; off >>= 1) {
        v0 += __shfl_down(v0, off, 64);
        v1 += __shfl_down(v1, off, 64);
    }
    if ((t & 63) == 0) { red[(t >> 6) * 2] = v0; red[(t >> 6) * 2 + 1] = v1; }
    __syncthreads();
    const float sum   = red[0] + red[2] + red[4] + red[6];
    const float sumsq = red[1] + red[3] + red[5] + red[7];
    const float mu  = sum * (1.0f / DNODE);
    const float var = sumsq * (1.0f / DNODE) - mu * mu;
    const float inv = rsqrtf(var + LN_EPS);
    sn[t] = (x - mu) * inv * gamma[t] + beta[t];
    __syncthreads();

    // 64 outputs (32 for a, 32 for b); 4 threads per output, 64 terms each.
    const int o = t >> 2, part = t & 3;
    const float* Wrow = (o < DHID) ? (Wa + (size_t)o * DNODE)
                                   : (Wb + (size_t)(o - DHID) * DNODE);
    const int base = part * 64;
    float acc = 0.f;
    #pragma unroll
    for (int k = 0; k < 64; k += 4) {
        const float4 w  = *(const float4*)(Wrow + base + k);
        const float4 xs = *(const float4*)(sn + base + k);
        acc += w.x * xs.x + w.y * xs.y + w.z * xs.z + w.w * xs.w;
    }
    acc += __shfl_xor(acc, 1, 64);
    acc += __shfl_xor(acc, 2, 64);
    if (part == 0) {
        if (o < DHID) a_vec[blk * DHID + o]          = (__bf16)(acc + ba[o]);
        else          b_vec[blk * DHID + (o - DHID)] = (__bf16)(acc + bb[o - DHID]);
    }
}

// ---------------------------------------------------------------------------
// Kernel 2: T[j, m] = sum_e Wo[m, e] * b[j, e], m = (p,d) in [0,4096)
// MFMA with M = m (Wo rows as A-operand, fp32->bf16 inline), N = j.
// C[m][n]: lane holds 4 consecutive m at fixed j -> one 8-B bf16x4 store/tile.
// Tm layout: [j][4096] row-major == flat (j*128+p)*32 + d, i.e. rows of the
// A-operand kernel 3 needs.
// ---------------------------------------------------------------------------
__global__ __launch_bounds__(256) void k2_build_T(
    const __bf16* __restrict__ b_vec, const float* __restrict__ Wo,
    __bf16* __restrict__ Tm)
{
    const int l = threadIdx.x & 63;
    const int w = threadIdx.x >> 6;
    const int j0 = blockIdx.y * 16;
    const int mg = blockIdx.x * 4 + w;        // m-group: 4 consecutive m-tiles
    const int row = l & 15, q = l >> 4, koff = q * 8;

    // B-operand: b rows (n = j), loaded once per wave
    const bf16x8 bfr = *(const bf16x8*)(b_vec + (j0 + row) * DHID + koff);

    #pragma unroll
    for (int tt = 0; tt < 4; ++tt) {
        const int m0 = (mg * 4 + tt) * 16;
        // A-operand: Wo rows (m = (p,d)), fp32 -> bf16 inline
        const float* wr = Wo + (size_t)(m0 + row) * 32 + koff;
        const float4 w0 = *(const float4*)(wr);
        const float4 w1 = *(const float4*)(wr + 4);
        bf16x8 afr;
        afr[0] = (__bf16)w0.x; afr[1] = (__bf16)w0.y;
        afr[2] = (__bf16)w0.z; afr[3] = (__bf16)w0.w;
        afr[4] = (__bf16)w1.x; afr[5] = (__bf16)w1.y;
        afr[6] = (__bf16)w1.z; afr[7] = (__bf16)w1.w;

        f32x4 acc = {0.f, 0.f, 0.f, 0.f};
        acc = __builtin_amdgcn_mfma_f32_16x16x32_bf16(afr, bfr, acc, 0, 0, 0);

        bf16x4 o;
        o[0] = (__bf16)acc[0]; o[1] = (__bf16)acc[1];
        o[2] = (__bf16)acc[2]; o[3] = (__bf16)acc[3];
        *(bf16x4*)(Tm + (size_t)(j0 + row) * 4096 + m0 + q * 4) = o;
    }
}

// ---------------------------------------------------------------------------
// Kernel 3: out[i, jp] = sum_d T[jp, d] * a[i, d] + bo[jp & 127]
// MFMA with M = jp (T rows as A-operand), N = i (a rows as B-operand).
// C[m][n]: lane holds out[i][jp0+q*4 .. +3] -> one global_store_dwordx4/tile.
// Bias varies along m: folded into acc init via a float4 load of bo.
// ---------------------------------------------------------------------------
__global__ __launch_bounds__(256) void k3_main(
    const __bf16* __restrict__ a_vec, const __bf16* __restrict__ Tm,
    const float* __restrict__ bo, float* __restrict__ out)
{
    const int l = threadIdx.x & 63;
    const int w = threadIdx.x >> 6;
    const int i0 = blockIdx.y * 16;
    const int row = l & 15, q = l >> 4, koff = q * 8;

    // B-operand: a rows (n = i), loaded once per wave
    const bf16x8 bfr = *(const bf16x8*)(a_vec + (i0 + row) * DHID + koff);

    const int g = blockIdx.x * 4 + w;         // jp-group: 8 consecutive jp-tiles
    #pragma unroll
    for (int tt = 0; tt < 8; ++tt) {
        const int jp0 = (g * 8 + tt) * 16;
        // A-operand: T rows (m = jp)
        const bf16x8 afr = *(const bf16x8*)(Tm + (size_t)(jp0 + row) * 32 + koff);
        // bias: bo[(jp0 + q*4 + r) & 127]; jp0 mult of 16, no wrap inside tile
        const float4 bv = *(const float4*)(bo + ((jp0 & (DPAIR - 1)) + q * 4));
        f32x4 acc = {bv.x, bv.y, bv.z, bv.w};
        acc = __builtin_amdgcn_mfma_f32_16x16x32_bf16(afr, bfr, acc, 0, 0, 0);

        f32x4* dst = (f32x4*)(out + (size_t)(i0 + row) * NOUT + jp0 + q * 4);
        __builtin_nontemporal_store(acc, dst);
    }
}

// ---------------------------------------------------------------------------
extern "C" void kernel_launch(void* const* d_in, const int* in_sizes, int n_in,
                              void* d_out, int out_size, void* d_ws, size_t ws_size,
                              hipStream_t stream)
{
    const float* s     = (const float*)d_in[0];
    const float* gamma = (const float*)d_in[1];
    const float* beta  = (const float*)d_in[2];
    const float* Wa    = (const float*)d_in[3];
    const float* ba    = (const float*)d_in[4];
    const float* Wb    = (const float*)d_in[5];
    const float* bb    = (const float*)d_in[6];
    const float* Wo    = (const float*)d_in[7];
    const float* bo    = (const float*)d_in[8];
    float* out = (float*)d_out;

    // Workspace layout (16B-aligned), total ~3.2 MB:
    char* ws = (char*)d_ws;
    __bf16* a_vec = (__bf16*)(ws);            // 384*32*2   = 24576 B
    __bf16* b_vec = (__bf16*)(ws + 24576);    // 384*32*2   = 24576 B
    __bf16* Tm    = (__bf16*)(ws + 49152);    // 384*4096*2 = 3145728 B

    // K1: 384 LN/proj blocks
    k1_ln_proj<<<384, 256, 0, stream>>>(s, gamma, beta, Wa, ba, Wb, bb,
                                        a_vec, b_vec);
    // K2: T  (M=4096 (p,d), N=384 j, K=32 e): 256 m-tiles x 24 j-tiles,
    //     4 m-tiles/wave -> grid (16, 24) x 4 waves
    k2_build_T<<<dim3(16, 24), 256, 0, stream>>>(b_vec, Wo, Tm);
    // K3: out (M=49152 jp, N=384 i, K=32 d): 3072 jp-tiles x 24 i-tiles,
    //     8 jp-tiles/wave -> grid (96, 24) x 4 waves
    k3_main<<<dim3(96, 24), 256, 0, stream>>>(a_vec, Tm, bo, out);
}

// Round 3
// 113.167 us; speedup vs baseline: 1.0301x; 1.0294x over previous
//
#include <hip/hip_runtime.h>
#include <hip/hip_bf16.h>

// Problem constants (B=1)
#define NTOK   384
#define DNODE  256
#define DPAIR  128
#define DHID   32
#define NOUT   49152   // NTOK * DPAIR, columns (fast axis) of the output
static constexpr float LN_EPS = 1e-5f;

typedef __bf16 bf16x8 __attribute__((ext_vector_type(8)));
typedef __bf16 bf16x4 __attribute__((ext_vector_type(4)));
typedef float  f32x4  __attribute__((ext_vector_type(4)));

// ---------------------------------------------------------------------------
// Kernel 1: LayerNorm + projections a = sn@Wa^T + ba, b = sn@Wb^T + bb
//           (one block per token row). Outputs bf16 [384][32] each.
// ---------------------------------------------------------------------------
__global__ __launch_bounds__(256) void k1_ln_proj(
    const float* __restrict__ s, const float* __restrict__ gamma,
    const float* __restrict__ beta,
    const float* __restrict__ Wa, const float* __restrict__ ba,
    const float* __restrict__ Wb, const float* __restrict__ bb,
    __bf16* __restrict__ a_vec, __bf16* __restrict__ b_vec)
{
    const int t = threadIdx.x;
    const int blk = blockIdx.x;

    __shared__ __align__(16) float sn[DNODE];
    __shared__ float red[8];

    const float x = s[blk * DNODE + t];
    float v0 = x, v1 = x * x;
    #pragma unroll
    for (int off = 32; off > 0; off >>= 1) {
        v0 += __shfl_down(v0, off, 64);
        v1 += __shfl_down(v1, off, 64);
    }
    if ((t & 63) == 0) { red[(t >> 6) * 2] = v0; red[(t >> 6) * 2 + 1] = v1; }
    __syncthreads();
    const float sum   = red[0] + red[2] + red[4] + red[6];
    const float sumsq = red[1] + red[3] + red[5] + red[7];
    const float mu  = sum * (1.0f / DNODE);
    const float var = sumsq * (1.0f / DNODE) - mu * mu;
    const float inv = rsqrtf(var + LN_EPS);
    sn[t] = (x - mu) * inv * gamma[t] + beta[t];
    __syncthreads();

    // 64 outputs (32 for a, 32 for b); 4 threads per output, 64 terms each.
    const int o = t >> 2, part = t & 3;
    const float* Wrow = (o < DHID) ? (Wa + (size_t)o * DNODE)
                                   : (Wb + (size_t)(o - DHID) * DNODE);
    const int base = part * 64;
    float acc = 0.f;
    #pragma unroll
    for (int k = 0; k < 64; k += 4) {
        const float4 w  = *(const float4*)(Wrow + base + k);
        const float4 xs = *(const float4*)(sn + base + k);
        acc += w.x * xs.x + w.y * xs.y + w.z * xs.z + w.w * xs.w;
    }
    acc += __shfl_xor(acc, 1, 64);
    acc += __shfl_xor(acc, 2, 64);
    if (part == 0) {
        if (o < DHID) a_vec[blk * DHID + o]          = (__bf16)(acc + ba[o]);
        else          b_vec[blk * DHID + (o - DHID)] = (__bf16)(acc + bb[o - DHID]);
    }
}

// ---------------------------------------------------------------------------
// Kernel 2: T[j, m] = sum_e Wo[m, e] * b[j, e], m = (p,d) in [0,4096)
// MFMA with M = m (Wo rows as A-operand, fp32->bf16 inline), N = j.
// Tm layout: [j][4096] row-major == flat (j*128+p)*32 + d.
// ---------------------------------------------------------------------------
__global__ __launch_bounds__(256) void k2_build_T(
    const __bf16* __restrict__ b_vec, const float* __restrict__ Wo,
    __bf16* __restrict__ Tm)
{
    const int l = threadIdx.x & 63;
    const int w = threadIdx.x >> 6;
    const int j0 = blockIdx.y * 16;
    const int mg = blockIdx.x * 4 + w;        // m-group: 4 consecutive m-tiles
    const int row = l & 15, q = l >> 4, koff = q * 8;

    // B-operand: b rows (n = j), loaded once per wave
    const bf16x8 bfr = *(const bf16x8*)(b_vec + (j0 + row) * DHID + koff);

    #pragma unroll
    for (int tt = 0; tt < 4; ++tt) {
        const int m0 = (mg * 4 + tt) * 16;
        // A-operand: Wo rows (m = (p,d)), fp32 -> bf16 inline
        const float* wr = Wo + (size_t)(m0 + row) * 32 + koff;
        const float4 w0 = *(const float4*)(wr);
        const float4 w1 = *(const float4*)(wr + 4);
        bf16x8 afr;
        afr[0] = (__bf16)w0.x; afr[1] = (__bf16)w0.y;
        afr[2] = (__bf16)w0.z; afr[3] = (__bf16)w0.w;
        afr[4] = (__bf16)w1.x; afr[5] = (__bf16)w1.y;
        afr[6] = (__bf16)w1.z; afr[7] = (__bf16)w1.w;

        f32x4 acc = {0.f, 0.f, 0.f, 0.f};
        acc = __builtin_amdgcn_mfma_f32_16x16x32_bf16(afr, bfr, acc, 0, 0, 0);

        bf16x4 o;
        o[0] = (__bf16)acc[0]; o[1] = (__bf16)acc[1];
        o[2] = (__bf16)acc[2]; o[3] = (__bf16)acc[3];
        *(bf16x4*)(Tm + (size_t)(j0 + row) * 4096 + m0 + q * 4) = o;
    }
}

// ---------------------------------------------------------------------------
// Kernel 3: out[i, jp] = sum_d T[jp, d] * a[i, d] + bo[jp & 127]
// MFMA with M = jp (T rows as A-operand), N = i (a rows as B-operand).
// Block = 16 i-rows x 256 jp-cols (16 tiles; 4 per wave). Accumulators are
// staged through LDS (row pad +4 floats -> only free 2-way conflicts), then
// stored row-wise: each wave-store = 64 lanes x float4 = 1 KB FULLY
// CONTIGUOUS (8 full 128-B L2 lines) -- no 64-B partial-line segments.
// ---------------------------------------------------------------------------
__global__ __launch_bounds__(256) void k3_main(
    const __bf16* __restrict__ a_vec, const __bf16* __restrict__ Tm,
    const float* __restrict__ bo, float* __restrict__ out)
{
    __shared__ __align__(16) float tilebuf[16][260];   // 16.25 KB, +16B row pad
    const int l = threadIdx.x & 63;
    const int w = threadIdx.x >> 6;
    const int i0 = blockIdx.y * 16;
    const int jpbase = blockIdx.x * 256;
    const int row = l & 15, q = l >> 4, koff = q * 8;

    // B-operand: a rows (n = i), loaded once per wave
    const bf16x8 bfr = *(const bf16x8*)(a_vec + (i0 + row) * DHID + koff);

    #pragma unroll
    for (int tt = 0; tt < 4; ++tt) {
        const int jpl = w * 64 + tt * 16;       // jp offset within block span
        const int jp0 = jpbase + jpl;
        // A-operand: T rows (m = jp)
        const bf16x8 afr = *(const bf16x8*)(Tm + (size_t)(jp0 + row) * 32 + koff);
        // bias varies along m; jpbase is a multiple of 256 so & 127 per tile
        const float4 bv = *(const float4*)(bo + ((jpl & (DPAIR - 1)) + q * 4));
        f32x4 acc = {bv.x, bv.y, bv.z, bv.w};
        acc = __builtin_amdgcn_mfma_f32_16x16x32_bf16(afr, bfr, acc, 0, 0, 0);
        // lane holds out[i0+row][jp0 + q*4 .. +3]
        *(f32x4*)&tilebuf[row][jpl + q * 4] = acc;
    }
    __syncthreads();

    // Store 16 rows x 1 KB; wave w handles rows {w, 4+w, 8+w, 12+w}.
    #pragma unroll
    for (int rr = 0; rr < 4; ++rr) {
        const int r = rr * 4 + w;
        const f32x4 v = *(const f32x4*)&tilebuf[r][l * 4];
        __builtin_nontemporal_store(
            v, (f32x4*)(out + (size_t)(i0 + r) * NOUT + jpbase + l * 4));
    }
}

// ---------------------------------------------------------------------------
extern "C" void kernel_launch(void* const* d_in, const int* in_sizes, int n_in,
                              void* d_out, int out_size, void* d_ws, size_t ws_size,
                              hipStream_t stream)
{
    const float* s     = (const float*)d_in[0];
    const float* gamma = (const float*)d_in[1];
    const float* beta  = (const float*)d_in[2];
    const float* Wa    = (const float*)d_in[3];
    const float* ba    = (const float*)d_in[4];
    const float* Wb    = (const float*)d_in[5];
    const float* bb    = (const float*)d_in[6];
    const float* Wo    = (const float*)d_in[7];
    const float* bo    = (const float*)d_in[8];
    float* out = (float*)d_out;

    // Workspace layout (16B-aligned), total ~3.2 MB:
    char* ws = (char*)d_ws;
    __bf16* a_vec = (__bf16*)(ws);            // 384*32*2   = 24576 B
    __bf16* b_vec = (__bf16*)(ws + 24576);    // 384*32*2   = 24576 B
    __bf16* Tm    = (__bf16*)(ws + 49152);    // 384*4096*2 = 3145728 B

    // K1: 384 LN/proj blocks
    k1_ln_proj<<<384, 256, 0, stream>>>(s, gamma, beta, Wa, ba, Wb, bb,
                                        a_vec, b_vec);
    // K2: T  (M=4096 (p,d), N=384 j, K=32 e): 256 m-tiles x 24 j-tiles
    k2_build_T<<<dim3(16, 24), 256, 0, stream>>>(b_vec, Wo, Tm);
    // K3: out: 192 jp-groups (256 cols each) x 24 i-tiles = 4608 blocks.
    //     Same-x blocks share a 16-KB Tm slice and land on the same XCD
    //     (192 % 8 == 0), so Tm re-reads are XCD-L2-local.
    k3_main<<<dim3(192, 24), 256, 0, stream>>>(a_vec, Tm, bo, out);
}

// Round 4
// 112.173 us; speedup vs baseline: 1.0392x; 1.0089x over previous
//
#include <hip/hip_runtime.h>
#include <hip/hip_bf16.h>

// Problem constants (B=1)
#define NTOK   384
#define DNODE  256
#define DPAIR  128
#define DHID   32
#define NOUT   49152   // NTOK * DPAIR, columns (fast axis) of the output
static constexpr float LN_EPS = 1e-5f;

typedef __bf16 bf16x8 __attribute__((ext_vector_type(8)));
typedef __bf16 bf16x4 __attribute__((ext_vector_type(4)));
typedef float  f32x4  __attribute__((ext_vector_type(4)));

// ---------------------------------------------------------------------------
// Kernel 1: LayerNorm + projections a = sn@Wa^T + ba, b = sn@Wb^T + bb
//           (one block per token row). Outputs bf16 [384][32] each.
// ---------------------------------------------------------------------------
__global__ __launch_bounds__(256) void k1_ln_proj(
    const float* __restrict__ s, const float* __restrict__ gamma,
    const float* __restrict__ beta,
    const float* __restrict__ Wa, const float* __restrict__ ba,
    const float* __restrict__ Wb, const float* __restrict__ bb,
    __bf16* __restrict__ a_vec, __bf16* __restrict__ b_vec)
{
    const int t = threadIdx.x;
    const int blk = blockIdx.x;

    __shared__ __align__(16) float sn[DNODE];
    __shared__ float red[8];

    const float x = s[blk * DNODE + t];
    float v0 = x, v1 = x * x;
    #pragma unroll
    for (int off = 32; off > 0; off >>= 1) {
        v0 += __shfl_down(v0, off, 64);
        v1 += __shfl_down(v1, off, 64);
    }
    if ((t & 63) == 0) { red[(t >> 6) * 2] = v0; red[(t >> 6) * 2 + 1] = v1; }
    __syncthreads();
    const float sum   = red[0] + red[2] + red[4] + red[6];
    const float sumsq = red[1] + red[3] + red[5] + red[7];
    const float mu  = sum * (1.0f / DNODE);
    const float var = sumsq * (1.0f / DNODE) - mu * mu;
    const float inv = rsqrtf(var + LN_EPS);
    sn[t] = (x - mu) * inv * gamma[t] + beta[t];
    __syncthreads();

    // 64 outputs (32 for a, 32 for b); 4 threads per output, 64 terms each.
    const int o = t >> 2, part = t & 3;
    const float* Wrow = (o < DHID) ? (Wa + (size_t)o * DNODE)
                                   : (Wb + (size_t)(o - DHID) * DNODE);
    const int base = part * 64;
    float acc = 0.f;
    #pragma unroll
    for (int k = 0; k < 64; k += 4) {
        const float4 w  = *(const float4*)(Wrow + base + k);
        const float4 xs = *(const float4*)(sn + base + k);
        acc += w.x * xs.x + w.y * xs.y + w.z * xs.z + w.w * xs.w;
    }
    acc += __shfl_xor(acc, 1, 64);
    acc += __shfl_xor(acc, 2, 64);
    if (part == 0) {
        if (o < DHID) a_vec[blk * DHID + o]          = (__bf16)(acc + ba[o]);
        else          b_vec[blk * DHID + (o - DHID)] = (__bf16)(acc + bb[o - DHID]);
    }
}

// ---------------------------------------------------------------------------
// Kernel 2: T[j, m] = sum_e Wo[m, e] * b[j, e], m = (p,d) in [0,4096)
// MFMA with M = m (Wo rows as A-operand, fp32->bf16 inline), N = j.
// Tm layout: [j][4096] row-major == flat (j*128+p)*32 + d.
// ---------------------------------------------------------------------------
__global__ __launch_bounds__(256) void k2_build_T(
    const __bf16* __restrict__ b_vec, const float* __restrict__ Wo,
    __bf16* __restrict__ Tm)
{
    const int l = threadIdx.x & 63;
    const int w = threadIdx.x >> 6;
    const int j0 = blockIdx.y * 16;
    const int mg = blockIdx.x * 4 + w;        // m-group: 4 consecutive m-tiles
    const int row = l & 15, q = l >> 4, koff = q * 8;

    // B-operand: b rows (n = j), loaded once per wave
    const bf16x8 bfr = *(const bf16x8*)(b_vec + (j0 + row) * DHID + koff);

    #pragma unroll
    for (int tt = 0; tt < 4; ++tt) {
        const int m0 = (mg * 4 + tt) * 16;
        // A-operand: Wo rows (m = (p,d)), fp32 -> bf16 inline
        const float* wr = Wo + (size_t)(m0 + row) * 32 + koff;
        const float4 w0 = *(const float4*)(wr);
        const float4 w1 = *(const float4*)(wr + 4);
        bf16x8 afr;
        afr[0] = (__bf16)w0.x; afr[1] = (__bf16)w0.y;
        afr[2] = (__bf16)w0.z; afr[3] = (__bf16)w0.w;
        afr[4] = (__bf16)w1.x; afr[5] = (__bf16)w1.y;
        afr[6] = (__bf16)w1.z; afr[7] = (__bf16)w1.w;

        f32x4 acc = {0.f, 0.f, 0.f, 0.f};
        acc = __builtin_amdgcn_mfma_f32_16x16x32_bf16(afr, bfr, acc, 0, 0, 0);

        bf16x4 o;
        o[0] = (__bf16)acc[0]; o[1] = (__bf16)acc[1];
        o[2] = (__bf16)acc[2]; o[3] = (__bf16)acc[3];
        *(bf16x4*)(Tm + (size_t)(j0 + row) * 4096 + m0 + q * 4) = o;
    }
}

// ---------------------------------------------------------------------------
// Kernel 3: out[i, jp] = sum_d T[jp, d] * a[i, d] + bo[jp & 127]
// MFMA with M = jp (T rows as A-operand), N = i (a rows as B-operand).
// Block = 16 i-rows x 256 jp-cols (16 tiles; 4 per wave). Accumulators are
// staged through LDS, then stored row-wise: each wave-store = 64 lanes x
// float4 = 1 KB fully contiguous. R4 change: PLAIN cached stores (NT removed)
// — NT was the one constant across all slow rounds; fillBuffer's plain
// stores hit 6 TB/s write while NT k3 appears stuck near 1.7 TB/s.
// ---------------------------------------------------------------------------
__global__ __launch_bounds__(256) void k3_main(
    const __bf16* __restrict__ a_vec, const __bf16* __restrict__ Tm,
    const float* __restrict__ bo, float* __restrict__ out)
{
    __shared__ __align__(16) float tilebuf[16][260];   // 16.25 KB, +16B row pad
    const int l = threadIdx.x & 63;
    const int w = threadIdx.x >> 6;
    const int i0 = blockIdx.y * 16;
    const int jpbase = blockIdx.x * 256;
    const int row = l & 15, q = l >> 4, koff = q * 8;

    // B-operand: a rows (n = i), loaded once per wave
    const bf16x8 bfr = *(const bf16x8*)(a_vec + (i0 + row) * DHID + koff);

    #pragma unroll
    for (int tt = 0; tt < 4; ++tt) {
        const int jpl = w * 64 + tt * 16;       // jp offset within block span
        const int jp0 = jpbase + jpl;
        // A-operand: T rows (m = jp)
        const bf16x8 afr = *(const bf16x8*)(Tm + (size_t)(jp0 + row) * 32 + koff);
        // bias varies along m; jpbase is a multiple of 256 so & 127 per tile
        const float4 bv = *(const float4*)(bo + ((jpl & (DPAIR - 1)) + q * 4));
        f32x4 acc = {bv.x, bv.y, bv.z, bv.w};
        acc = __builtin_amdgcn_mfma_f32_16x16x32_bf16(afr, bfr, acc, 0, 0, 0);
        // lane holds out[i0+row][jp0 + q*4 .. +3]
        *(f32x4*)&tilebuf[row][jpl + q * 4] = acc;
    }
    __syncthreads();

    // Store 16 rows x 1 KB; wave w handles rows {w, 4+w, 8+w, 12+w}.
    #pragma unroll
    for (int rr = 0; rr < 4; ++rr) {
        const int r = rr * 4 + w;
        const f32x4 v = *(const f32x4*)&tilebuf[r][l * 4];
        *(f32x4*)(out + (size_t)(i0 + r) * NOUT + jpbase + l * 4) = v;
    }
}

// ---------------------------------------------------------------------------
extern "C" void kernel_launch(void* const* d_in, const int* in_sizes, int n_in,
                              void* d_out, int out_size, void* d_ws, size_t ws_size,
                              hipStream_t stream)
{
    const float* s     = (const float*)d_in[0];
    const float* gamma = (const float*)d_in[1];
    const float* beta  = (const float*)d_in[2];
    const float* Wa    = (const float*)d_in[3];
    const float* ba    = (const float*)d_in[4];
    const float* Wb    = (const float*)d_in[5];
    const float* bb    = (const float*)d_in[6];
    const float* Wo    = (const float*)d_in[7];
    const float* bo    = (const float*)d_in[8];
    float* out = (float*)d_out;

    // Workspace layout (16B-aligned), total ~3.2 MB:
    char* ws = (char*)d_ws;
    __bf16* a_vec = (__bf16*)(ws);            // 384*32*2   = 24576 B
    __bf16* b_vec = (__bf16*)(ws + 24576);    // 384*32*2   = 24576 B
    __bf16* Tm    = (__bf16*)(ws + 49152);    // 384*4096*2 = 3145728 B

    // K1: 384 LN/proj blocks
    k1_ln_proj<<<384, 256, 0, stream>>>(s, gamma, beta, Wa, ba, Wb, bb,
                                        a_vec, b_vec);
    // K2: T  (M=4096 (p,d), N=384 j, K=32 e): 256 m-tiles x 24 j-tiles
    k2_build_T<<<dim3(16, 24), 256, 0, stream>>>(b_vec, Wo, Tm);
    // K3: out: 192 jp-groups (256 cols each) x 24 i-tiles = 4608 blocks.
    k3_main<<<dim3(192, 24), 256, 0, stream>>>(a_vec, Tm, bo, out);
}